// Round 1
// baseline (887.024 us; speedup 1.0000x reference)
//
#include <hip/hip_runtime.h>
#include <stdint.h>

// Problem constants
#define B_DIM   4096
#define IN_DIM  2048
#define OUT_DIM 2048
#define NC      8                    // N_COEFF = GRID_SIZE + SPLINE_ORDER = 8
#define KS      (IN_DIM * NC)        // 16384 spline-K
#define KTOT    (KS + IN_DIM)        // 18432 augmented K (spline + base)
#define TILE    128
#define BK      32

typedef __bf16 bf16x8 __attribute__((ext_vector_type(8)));
typedef float  floatx4 __attribute__((ext_vector_type(4)));
typedef unsigned short ushortx8 __attribute__((ext_vector_type(8)));

__device__ __forceinline__ unsigned short f2bf(float f) {
  // round-to-nearest-even f32 -> bf16 (no NaN expected in this problem)
  unsigned int u = __float_as_uint(f);
  return (unsigned short)((u + 0x7FFFu + ((u >> 16) & 1u)) >> 16);
}

__device__ __forceinline__ void load_lds16(const void* g, void* l) {
  // async global->LDS, 16B/lane; LDS dst is wave-uniform base + lane*16
  __builtin_amdgcn_global_load_lds(
      (const __attribute__((address_space(1))) void*)g,
      (__attribute__((address_space(3))) void*)l, 16, 0, 0);
}

// ---------------------------------------------------------------------------
// Stage A: A[b, i*8+c] = bf16(basis[b,i,c]);  A[b, 16384+i] = bf16(x[b,i])
// ---------------------------------------------------------------------------
__global__ __launch_bounds__(256) void build_A(const float* __restrict__ x,
                                               const float* __restrict__ grid,
                                               unsigned short* __restrict__ Abuf) {
  __shared__ float g[12];
  int t = threadIdx.x;
  if (t < 12) g[t] = grid[t];   // all grid rows identical; row 0 suffices
  __syncthreads();
  int idx = blockIdx.x * 256 + t;     // over B*IN = 8.4M
  float xv = x[idx];
  float bs[11];
#pragma unroll
  for (int j = 0; j < 11; ++j)
    bs[j] = (xv >= g[j] && xv < g[j + 1]) ? 1.0f : 0.0f;
#pragma unroll
  for (int p = 1; p <= 3; ++p) {
#pragma unroll
    for (int j = 0; j + p < 11; ++j) {
      float t1 = (xv - g[j])         / (g[j + p]     - g[j]     + 1e-8f);
      float t2 = (g[j + p + 1] - xv) / (g[j + p + 1] - g[j + 1] + 1e-8f);
      bs[j] = t1 * bs[j] + t2 * bs[j + 1];
    }
  }
  int b = idx >> 11;                 // / IN_DIM
  int i = idx & (IN_DIM - 1);
  ushortx8 pk;
#pragma unroll
  for (int c = 0; c < 8; ++c) pk[c] = f2bf(bs[c]);
  *(ushortx8*)&Abuf[(size_t)b * KTOT + (size_t)i * 8] = pk;
  Abuf[(size_t)b * KTOT + KS + i] = f2bf(xv);
}

// ---------------------------------------------------------------------------
// Stage B: Bm[o, i*8+c] = bf16(round(sw*32)/32);  Bm[o, 16384+i] = bf16(bw[o,i])
// ---------------------------------------------------------------------------
__global__ __launch_bounds__(256) void build_B(const float* __restrict__ sw,
                                               const float* __restrict__ bw,
                                               unsigned short* __restrict__ Bbuf) {
  int idx = blockIdx.x * 256 + threadIdx.x;   // over OUT*IN = 4.2M
  const float4* swv = (const float4*)sw;
  float4 w0 = swv[(size_t)idx * 2];
  float4 w1 = swv[(size_t)idx * 2 + 1];
  ushortx8 pk;
  pk[0] = f2bf(rintf(w0.x * 32.f) * 0.03125f);
  pk[1] = f2bf(rintf(w0.y * 32.f) * 0.03125f);
  pk[2] = f2bf(rintf(w0.z * 32.f) * 0.03125f);
  pk[3] = f2bf(rintf(w0.w * 32.f) * 0.03125f);
  pk[4] = f2bf(rintf(w1.x * 32.f) * 0.03125f);
  pk[5] = f2bf(rintf(w1.y * 32.f) * 0.03125f);
  pk[6] = f2bf(rintf(w1.z * 32.f) * 0.03125f);
  pk[7] = f2bf(rintf(w1.w * 32.f) * 0.03125f);
  int o = idx >> 11;
  int i = idx & (IN_DIM - 1);
  *(ushortx8*)&Bbuf[(size_t)o * KTOT + (size_t)i * 8] = pk;
  Bbuf[(size_t)o * KTOT + KS + i] = f2bf(bw[idx]);
}

// ---------------------------------------------------------------------------
// C[b,o] = sum_k A[b,k] * Bm[o,k]   (both K-major; m97-style 128x128 tile)
// ---------------------------------------------------------------------------
__global__ __launch_bounds__(256) void gemm_bt(const unsigned short* __restrict__ A,
                                               const unsigned short* __restrict__ Bm,
                                               float* __restrict__ C) {
  __shared__ unsigned short As[TILE * BK];   // 8 KB, row-major [128][32], no pad
  __shared__ unsigned short Bs[TILE * BK];   // 8 KB
  const int tid  = threadIdx.x;
  const int wv   = tid >> 6;
  const int lane = tid & 63;
  const int row0 = blockIdx.y * TILE;   // M block (b)
  const int col0 = blockIdx.x * TILE;   // N block (o)

  // staging: chunk = it*256 + tid; row = chunk>>2, colgroup = chunk&3 (8 elems)
  const int r  = tid >> 2;
  const int cg = tid & 3;
  const unsigned short* aP0 = A  + (size_t)(row0 + r) * KTOT + cg * 8;
  const unsigned short* aP1 = aP0 + (size_t)64 * KTOT;
  const unsigned short* bP0 = Bm + (size_t)(col0 + r) * KTOT + cg * 8;
  const unsigned short* bP1 = bP0 + (size_t)64 * KTOT;
  unsigned short* ldsA = As + wv * 512;   // wave-uniform: wv*1024 bytes
  unsigned short* ldsB = Bs + wv * 512;

  // compute-side fragment addressing (A[m=lane&15][k=quad*8+j], m89/m120 layout)
  const int wr = wv >> 1, wc = wv & 1;    // wave -> 64x64 quadrant
  const int lm = lane & 15, lq = lane >> 4;
  const unsigned short* rdA = As + (wr * 64 + lm) * BK + lq * 8;
  const unsigned short* rdB = Bs + (wc * 64 + lm) * BK + lq * 8;

  floatx4 acc[4][4];
#pragma unroll
  for (int i = 0; i < 4; ++i)
#pragma unroll
    for (int j = 0; j < 4; ++j) acc[i][j] = floatx4{0.f, 0.f, 0.f, 0.f};

  for (int k0 = 0; k0 < KTOT; k0 += BK) {
    load_lds16(aP0, ldsA);
    load_lds16(aP1, ldsA + 2048);   // +4096 bytes
    load_lds16(bP0, ldsB);
    load_lds16(bP1, ldsB + 2048);
    aP0 += BK; aP1 += BK; bP0 += BK; bP1 += BK;
    __syncthreads();   // drains vmcnt(0): LDS writes visible

    bf16x8 af[4], bfr[4];
#pragma unroll
    for (int i = 0; i < 4; ++i) af[i]  = *(const bf16x8*)(rdA + i * 16 * BK);
#pragma unroll
    for (int i = 0; i < 4; ++i) bfr[i] = *(const bf16x8*)(rdB + i * 16 * BK);
#pragma unroll
    for (int mt = 0; mt < 4; ++mt)
#pragma unroll
      for (int nt = 0; nt < 4; ++nt)
        acc[mt][nt] = __builtin_amdgcn_mfma_f32_16x16x32_bf16(
            af[mt], bfr[nt], acc[mt][nt], 0, 0, 0);
    __syncthreads();   // all reads done before next staging overwrites
  }

  // epilogue: C/D layout col=lane&15, row=(lane>>4)*4+reg (m89/m91 verified)
#pragma unroll
  for (int mt = 0; mt < 4; ++mt) {
#pragma unroll
    for (int nt = 0; nt < 4; ++nt) {
      int rr = row0 + wr * 64 + mt * 16 + lq * 4;
      int cc = col0 + wc * 64 + nt * 16 + lm;
#pragma unroll
      for (int q = 0; q < 4; ++q)
        C[(size_t)(rr + q) * OUT_DIM + cc] = acc[mt][nt][q];
    }
  }
}

extern "C" void kernel_launch(void* const* d_in, const int* in_sizes, int n_in,
                              void* d_out, int out_size, void* d_ws, size_t ws_size,
                              hipStream_t stream) {
  const float* x    = (const float*)d_in[0];
  const float* bw   = (const float*)d_in[1];
  const float* sw   = (const float*)d_in[2];
  const float* grid = (const float*)d_in[3];
  float* out = (float*)d_out;

  // workspace: A_bf16 [4096][18432] (151 MB) then B_bf16 [2048][18432] (75.5 MB)
  unsigned short* Abuf = (unsigned short*)d_ws;
  unsigned short* Bbuf = Abuf + (size_t)B_DIM * KTOT;

  hipLaunchKernelGGL(build_A, dim3(B_DIM * IN_DIM / 256), dim3(256), 0, stream,
                     x, grid, Abuf);
  hipLaunchKernelGGL(build_B, dim3(OUT_DIM * IN_DIM / 256), dim3(256), 0, stream,
                     sw, bw, Bbuf);
  hipLaunchKernelGGL(gemm_bt, dim3(OUT_DIM / TILE, B_DIM / TILE), dim3(256), 0,
                     stream, Abuf, Bbuf, out);
}

// Round 2
// 697.678 us; speedup vs baseline: 1.2714x; 1.2714x over previous
//
#include <hip/hip_runtime.h>
#include <stdint.h>

// Problem constants
#define B_DIM   4096
#define IN_DIM  2048
#define OUT_DIM 2048
#define NC      8                    // N_COEFF = GRID_SIZE + SPLINE_ORDER = 8
#define KS      (IN_DIM * NC)        // 16384 spline-K
#define KTOT    (KS + IN_DIM)        // 18432 augmented K (spline + base)
#define KHALF   (KTOT / 2)           // 9216, divisible by BK
#define TILE    128
#define BK      32

typedef __bf16 bf16x8 __attribute__((ext_vector_type(8)));
typedef float  floatx4 __attribute__((ext_vector_type(4)));
typedef unsigned short ushortx8 __attribute__((ext_vector_type(8)));

__device__ __forceinline__ unsigned short f2bf(float f) {
  unsigned int u = __float_as_uint(f);
  return (unsigned short)((u + 0x7FFFu + ((u >> 16) & 1u)) >> 16);
}

__device__ __forceinline__ void load_lds16(const void* g, void* l) {
  __builtin_amdgcn_global_load_lds(
      (const __attribute__((address_space(1))) void*)g,
      (__attribute__((address_space(3))) void*)l, 16, 0, 0);
}

// ---------------------------------------------------------------------------
// Stage A: A[b, i*8+c] = bf16(basis[b,i,c]);  A[b, 16384+i] = bf16(x[b,i])
// Denominators of the Cox-de Boor recurrence are x-independent -> precompute
// reciprocals once per block (removes 54 fp32 divides per thread; R1 showed
// build_A was VALU-bound at ~315 us because of them).
// ---------------------------------------------------------------------------
__global__ __launch_bounds__(256) void build_A(const float* __restrict__ x,
                                               const float* __restrict__ grid,
                                               unsigned short* __restrict__ Abuf) {
  __shared__ float g[12];
  __shared__ float rec[3][12];   // rec[p-1][j] = 1/(g[j+p]-g[j]+1e-8)
  int t = threadIdx.x;
  if (t < 12) g[t] = grid[t];   // all grid rows identical; row 0 suffices
  __syncthreads();
  if (t < 36) {
    int p = t / 12 + 1, j = t % 12;
    if (j + p <= 11) rec[p - 1][j] = 1.0f / (g[j + p] - g[j] + 1e-8f);
  }
  __syncthreads();
  int idx = blockIdx.x * 256 + t;     // over B*IN = 8.4M
  float xv = x[idx];
  float bs[11];
#pragma unroll
  for (int j = 0; j < 11; ++j)
    bs[j] = (xv >= g[j] && xv < g[j + 1]) ? 1.0f : 0.0f;
#pragma unroll
  for (int p = 1; p <= 3; ++p) {
#pragma unroll
    for (int j = 0; j + p < 11; ++j) {
      float t1 = (xv - g[j])         * rec[p - 1][j];
      float t2 = (g[j + p + 1] - xv) * rec[p - 1][j + 1];
      bs[j] = t1 * bs[j] + t2 * bs[j + 1];
    }
  }
  int b = idx >> 11;                 // / IN_DIM
  int i = idx & (IN_DIM - 1);
  ushortx8 pk;
#pragma unroll
  for (int c = 0; c < 8; ++c) pk[c] = f2bf(bs[c]);
  *(ushortx8*)&Abuf[(size_t)b * KTOT + (size_t)i * 8] = pk;
  Abuf[(size_t)b * KTOT + KS + i] = f2bf(xv);
}

// ---------------------------------------------------------------------------
// Stage B: Bm[o, i*8+c] = bf16(round(sw*32)/32);  Bm[o, 16384+i] = bf16(bw[o,i])
// ---------------------------------------------------------------------------
__global__ __launch_bounds__(256) void build_B(const float* __restrict__ sw,
                                               const float* __restrict__ bw,
                                               unsigned short* __restrict__ Bbuf) {
  int idx = blockIdx.x * 256 + threadIdx.x;   // over OUT*IN = 4.2M
  const float4* swv = (const float4*)sw;
  float4 w0 = swv[(size_t)idx * 2];
  float4 w1 = swv[(size_t)idx * 2 + 1];
  ushortx8 pk;
  pk[0] = f2bf(rintf(w0.x * 32.f) * 0.03125f);
  pk[1] = f2bf(rintf(w0.y * 32.f) * 0.03125f);
  pk[2] = f2bf(rintf(w0.z * 32.f) * 0.03125f);
  pk[3] = f2bf(rintf(w0.w * 32.f) * 0.03125f);
  pk[4] = f2bf(rintf(w1.x * 32.f) * 0.03125f);
  pk[5] = f2bf(rintf(w1.y * 32.f) * 0.03125f);
  pk[6] = f2bf(rintf(w1.z * 32.f) * 0.03125f);
  pk[7] = f2bf(rintf(w1.w * 32.f) * 0.03125f);
  int o = idx >> 11;
  int i = idx & (IN_DIM - 1);
  *(ushortx8*)&Bbuf[(size_t)o * KTOT + (size_t)i * 8] = pk;
  Bbuf[(size_t)o * KTOT + KS + i] = f2bf(bw[idx]);
}

// ---------------------------------------------------------------------------
// C[b,o] = sum_k A[b,k] * Bm[o,k].  Split-K over blockIdx.z: z=0 covers
// [0,klen) -> writes C0 (d_out); z=1 covers [klen,2*klen) -> writes C1 (ws
// partial).  R1: 512 blocks = 2 blk/CU starved occupancy (23.5%); z-split
// doubles grid to 1024 -> 4 blk/CU.
// ---------------------------------------------------------------------------
__global__ __launch_bounds__(256) void gemm_bt(const unsigned short* __restrict__ A,
                                               const unsigned short* __restrict__ Bm,
                                               float* __restrict__ C0,
                                               float* __restrict__ C1,
                                               int klen) {
  __shared__ unsigned short As[TILE * BK];   // 8 KB, row-major [128][32], no pad
  __shared__ unsigned short Bs[TILE * BK];   // 8 KB
  const int tid  = threadIdx.x;
  const int wv   = tid >> 6;
  const int lane = tid & 63;
  const int row0 = blockIdx.y * TILE;   // M block (b)
  const int col0 = blockIdx.x * TILE;   // N block (o)
  const int kz   = blockIdx.z;
  const int kbase = kz * klen;

  const int r  = tid >> 2;
  const int cg = tid & 3;
  const unsigned short* aP0 = A  + (size_t)(row0 + r) * KTOT + kbase + cg * 8;
  const unsigned short* aP1 = aP0 + (size_t)64 * KTOT;
  const unsigned short* bP0 = Bm + (size_t)(col0 + r) * KTOT + kbase + cg * 8;
  const unsigned short* bP1 = bP0 + (size_t)64 * KTOT;
  unsigned short* ldsA = As + wv * 512;
  unsigned short* ldsB = Bs + wv * 512;

  const int wr = wv >> 1, wc = wv & 1;    // wave -> 64x64 quadrant
  const int lm = lane & 15, lq = lane >> 4;
  const unsigned short* rdA = As + (wr * 64 + lm) * BK + lq * 8;
  const unsigned short* rdB = Bs + (wc * 64 + lm) * BK + lq * 8;

  floatx4 acc[4][4];
#pragma unroll
  for (int i = 0; i < 4; ++i)
#pragma unroll
    for (int j = 0; j < 4; ++j) acc[i][j] = floatx4{0.f, 0.f, 0.f, 0.f};

  for (int k0 = 0; k0 < klen; k0 += BK) {
    load_lds16(aP0, ldsA);
    load_lds16(aP1, ldsA + 2048);
    load_lds16(bP0, ldsB);
    load_lds16(bP1, ldsB + 2048);
    aP0 += BK; aP1 += BK; bP0 += BK; bP1 += BK;
    __syncthreads();

    bf16x8 af[4], bfr[4];
#pragma unroll
    for (int i = 0; i < 4; ++i) af[i]  = *(const bf16x8*)(rdA + i * 16 * BK);
#pragma unroll
    for (int i = 0; i < 4; ++i) bfr[i] = *(const bf16x8*)(rdB + i * 16 * BK);
#pragma unroll
    for (int mt = 0; mt < 4; ++mt)
#pragma unroll
      for (int nt = 0; nt < 4; ++nt)
        acc[mt][nt] = __builtin_amdgcn_mfma_f32_16x16x32_bf16(
            af[mt], bfr[nt], acc[mt][nt], 0, 0, 0);
    __syncthreads();
  }

  float* __restrict__ C = kz ? C1 : C0;   // wave-uniform branch
#pragma unroll
  for (int mt = 0; mt < 4; ++mt) {
#pragma unroll
    for (int nt = 0; nt < 4; ++nt) {
      int rr = row0 + wr * 64 + mt * 16 + lq * 4;
      int cc = col0 + wc * 64 + nt * 16 + lm;
#pragma unroll
      for (int q = 0; q < 4; ++q)
        C[(size_t)(rr + q) * OUT_DIM + cc] = acc[mt][nt][q];
    }
  }
}

// out += part, float4-vectorized over 8.4M elements
__global__ __launch_bounds__(256) void reduce_add(float* __restrict__ out,
                                                  const float* __restrict__ part) {
  int i = blockIdx.x * 256 + threadIdx.x;
  float4 a = ((const float4*)out)[i];
  float4 p = ((const float4*)part)[i];
  a.x += p.x; a.y += p.y; a.z += p.z; a.w += p.w;
  ((float4*)out)[i] = a;
}

extern "C" void kernel_launch(void* const* d_in, const int* in_sizes, int n_in,
                              void* d_out, int out_size, void* d_ws, size_t ws_size,
                              hipStream_t stream) {
  const float* x    = (const float*)d_in[0];
  const float* bw   = (const float*)d_in[1];
  const float* sw   = (const float*)d_in[2];
  const float* grid = (const float*)d_in[3];
  float* out = (float*)d_out;

  // ws layout: A_bf16 [4096][18432] (151 MB) | B_bf16 [2048][18432] (75.5 MB)
  //            | optional split-K partial C [4096][2048] f32 (33.5 MB)
  unsigned short* Abuf = (unsigned short*)d_ws;
  unsigned short* Bbuf = Abuf + (size_t)B_DIM * KTOT;
  float* Cpart = (float*)(Bbuf + (size_t)OUT_DIM * KTOT);
  const size_t need_split =
      ((size_t)B_DIM + OUT_DIM) * KTOT * 2 + (size_t)B_DIM * OUT_DIM * 4;
  const bool split = ws_size >= need_split;   // constant across calls -> capture-safe

  hipLaunchKernelGGL(build_A, dim3(B_DIM * IN_DIM / 256), dim3(256), 0, stream,
                     x, grid, Abuf);
  hipLaunchKernelGGL(build_B, dim3(OUT_DIM * IN_DIM / 256), dim3(256), 0, stream,
                     sw, bw, Bbuf);
  if (split) {
    hipLaunchKernelGGL(gemm_bt, dim3(OUT_DIM / TILE, B_DIM / TILE, 2), dim3(256),
                       0, stream, Abuf, Bbuf, out, Cpart, KHALF);
    hipLaunchKernelGGL(reduce_add, dim3(B_DIM * OUT_DIM / 4 / 256), dim3(256),
                       0, stream, out, Cpart);
  } else {
    hipLaunchKernelGGL(gemm_bt, dim3(OUT_DIM / TILE, B_DIM / TILE, 1), dim3(256),
                       0, stream, Abuf, Bbuf, out, (float*)nullptr, KTOT);
  }
}